// Round 24
// baseline (387.771 us; speedup 1.0000x reference)
//
#include <hip/hip_runtime.h>
#include <hip/hip_bf16.h>

#define EPSV 1e-5f
#define NBUCK_C 400
using u16 = unsigned short;
using u32 = unsigned int;
typedef __attribute__((ext_vector_type(8))) short short8;
typedef __attribute__((ext_vector_type(4))) float f32x4;

__device__ __forceinline__ u16 f2bf(float f) {
  __hip_bfloat16 h = __float2bfloat16(f);
  u16 u; __builtin_memcpy(&u, &h, 2); return u;
}

__device__ __forceinline__ void gload16(const void* g, void* l) {
  __builtin_amdgcn_global_load_lds(
      (const __attribute__((address_space(1))) void*)g,
      (__attribute__((address_space(3))) void*)l, 16, 0, 0);
}

// packed 2x u16 max (bf16 >= 0 orders as u16; mask-compare per half)
__device__ __forceinline__ u32 mx2(u32 a, u32 b) {
  u32 ah = a & 0xFFFF0000u, bh = b & 0xFFFF0000u;
  u32 al = a & 0x0000FFFFu, bl = b & 0x0000FFFFu;
  return (ah > bh ? ah : bh) | (al > bl ? al : bl);
}
__device__ __forceinline__ uint4 mx4(uint4 a, uint4 b) {
  return make_uint4(mx2(a.x, b.x), mx2(a.y, b.y), mx2(a.z, b.z), mx2(a.w, b.w));
}

// gather one node's 8-col slice (uint4) over its neighbor list
__device__ __forceinline__ uint4 gather_row(const u16* __restrict__ m,
                                            const int* __restrict__ csr,
                                            int base, int dg, int gl) {
  uint4 mx = make_uint4(0u, 0u, 0u, 0u);
  int i = 0;
  for (; i + 4 <= dg; i += 4) {
    const int u0 = csr[base + i + 0];
    const int u1 = csr[base + i + 1];
    const int u2 = csr[base + i + 2];
    const int u3 = csr[base + i + 3];
    const uint4 v0 = *(const uint4*)&m[(size_t)u0 * 64 + gl * 8];
    const uint4 v1 = *(const uint4*)&m[(size_t)u1 * 64 + gl * 8];
    const uint4 v2 = *(const uint4*)&m[(size_t)u2 * 64 + gl * 8];
    const uint4 v3 = *(const uint4*)&m[(size_t)u3 * 64 + gl * 8];
    mx = mx4(mx, mx4(mx4(v0, v1), mx4(v2, v3)));
  }
  for (; i < dg; ++i) {
    const int u = csr[base + i];
    mx = mx4(mx, *(const uint4*)&m[(size_t)u * 64 + gl * 8]);
  }
  return mx;
}

// ---------------------------------------------------------------------------
// Collapsed encoder + fused layer-0 pool, BM=64 all-reg-staged (latency floor
// declared; do not touch).
// ---------------------------------------------------------------------------
struct EncR { float4 a[4]; short8 b[2]; };

__global__ __launch_bounds__(256) void enc_fused64(
    const float* __restrict__ x0, const float* __restrict__ x1,
    const u16* __restrict__ W0, const u16* __restrict__ W1,
    const float* __restrict__ beff0, const float* __restrict__ beff1,
    const u16* __restrict__ Wp, const float* __restrict__ bp,
    u16* __restrict__ out, u16* __restrict__ mout, int M) {
  __shared__ u16 sA[64 * 64];
  __shared__ u16 sB[64 * 64];
  const int tid = threadIdx.x;
  const int l = tid & 63;
  const int w = tid >> 6;
  const int row0 = blockIdx.x * 64;
  const int lc = l & 15;
  const int koff = (l >> 4) * 8;

  f32x4 acc[4];
#pragma unroll
  for (int nf = 0; nf < 4; ++nf) acc[nf] = f32x4{0.f, 0.f, 0.f, 0.f};

  auto loadstep = [&](EncR& rs, int s) {
    const int ph = s >= 8;
    const float* X = ph ? x1 : x0;
    const u16* W = ph ? W1 : W0;
    const int lda = ph ? 256 : 512;
    const int kb = (s - (ph ? 8 : 0)) * 64;
#pragma unroll
    for (int c = 0; c < 2; ++c) {
      const int r = c * 32 + (tid >> 3);
      const int gr = min(row0 + r, M - 1);
      const float* gp = &X[(size_t)gr * lda + kb + ((tid & 7) << 3)];
      rs.a[c * 2] = *(const float4*)gp;
      rs.a[c * 2 + 1] = *(const float4*)(gp + 4);
    }
#pragma unroll
    for (int i = 0; i < 2; ++i) {
      const int s2 = tid * 2 + i;
      const int rb = s2 >> 3, sl = s2 & 7;
      rs.b[i] = *(const short8*)&W[rb * lda + kb + sl * 8];
    }
  };
  auto storestep = [&](const EncR& rs) {
#pragma unroll
    for (int c = 0; c < 2; ++c) {
      const int r = c * 32 + (tid >> 3);
      const int ssl = tid & 7;
      short8 pk;
#pragma unroll
      for (int j = 0; j < 4; ++j) pk[j] = (short)f2bf(rs.a[c * 2][j]);
#pragma unroll
      for (int j = 0; j < 4; ++j) pk[4 + j] = (short)f2bf(rs.a[c * 2 + 1][j]);
      *(short8*)&sA[r * 64 + ((ssl ^ (r & 7)) << 3)] = pk;
    }
#pragma unroll
    for (int i = 0; i < 2; ++i) {
      const int s2 = tid * 2 + i;
      const int rb = s2 >> 3, sl = s2 & 7;
      *(short8*)&sB[rb * 64 + ((sl ^ (rb & 7)) << 3)] = rs.b[i];
    }
  };
  auto compute = [&]() {
#pragma unroll
    for (int kk = 0; kk < 2; ++kk) {
      const int r = w * 16 + lc;
      const int sl = kk * 4 + (l >> 4);
      const short8 af = *(const short8*)&sA[r * 64 + ((sl ^ (r & 7)) << 3)];
#pragma unroll
      for (int nf = 0; nf < 4; ++nf) {
        const int rb = nf * 16 + lc;
        const short8 bf = *(const short8*)&sB[rb * 64 + ((sl ^ (rb & 7)) << 3)];
        acc[nf] = __builtin_amdgcn_mfma_f32_16x16x32_bf16(af, bf, acc[nf], 0, 0, 0);
      }
    }
  };

  EncR rA, rB;
  loadstep(rA, 0);
  for (int s = 0; s < 12; s += 2) {
    loadstep(rB, s + 1);
    storestep(rA);
    __syncthreads();
    compute();
    __syncthreads();
    if (s + 2 < 12) loadstep(rA, s + 2);
    storestep(rB);
    __syncthreads();
    compute();
    __syncthreads();
  }

  // epilogue 1: feat -> global + LDS restage (bf16, swizzled element layout)
  const int lj = l >> 4;
#pragma unroll
  for (int nf = 0; nf < 4; ++nf) {
    const int col = nf * 16 + lc;
    const float sh = beff0[col] + beff1[col];
#pragma unroll
    for (int j = 0; j < 4; ++j) {
      const int r = w * 16 + lj * 4 + j;
      const u16 hv = f2bf(acc[nf][j] + sh);
      sA[r * 64 + ((((col >> 3) ^ (r & 7)) << 3) | (col & 7))] = hv;
      const int row = row0 + r;
      if (row < M) out[(size_t)row * 64 + col] = hv;
    }
  }
  __syncthreads();

  // pool: m = relu(feat @ Wp^T + bp)
  f32x4 acc2[4];
#pragma unroll
  for (int nf = 0; nf < 4; ++nf) acc2[nf] = f32x4{0.f, 0.f, 0.f, 0.f};
#pragma unroll
  for (int kk = 0; kk < 2; ++kk) {
    const int r = w * 16 + lc;
    const int sl = kk * 4 + (l >> 4);
    const short8 af = *(const short8*)&sA[r * 64 + ((sl ^ (r & 7)) << 3)];
#pragma unroll
    for (int nf = 0; nf < 4; ++nf) {
      const short8 bf =
          *(const short8*)&Wp[(size_t)(nf * 16 + lc) * 64 + kk * 32 + koff];
      acc2[nf] = __builtin_amdgcn_mfma_f32_16x16x32_bf16(af, bf, acc2[nf], 0, 0, 0);
    }
  }
#pragma unroll
  for (int nf = 0; nf < 4; ++nf) {
    const int col = nf * 16 + lc;
    const float sh = bp[col];
#pragma unroll
    for (int j = 0; j < 4; ++j) {
      const int row = row0 + w * 16 + lj * 4 + j;
      if (row < M)
        mout[(size_t)row * 64 + col] = f2bf(fmaxf(acc2[nf][j] + sh, 0.f));
    }
  }
}

// ---------------------------------------------------------------------------
// Fused SAGE layer with IN-KERNEL gather (agg -> swizzled sA2 LDS, no global
// round-trip): h = relu(A@Ws^T + agg@Wn^T + b) -> Hout, next-layer pool
// m = relu(h @ Wp^T + bp) -> Mout. magg = previous pool buffer (read-only;
// Mout is a DIFFERENT buffer to avoid inter-block races). BM=128.
// ---------------------------------------------------------------------------
__global__ __launch_bounds__(256) void sage_g_fused(
    const u16* __restrict__ A, const u16* __restrict__ magg,
    const int* __restrict__ csr, const int* __restrict__ rp,
    const u16* __restrict__ B, const u16* __restrict__ B2,
    const float* __restrict__ bias, const u16* __restrict__ Wp,
    const float* __restrict__ bp, u16* __restrict__ Hout,
    u16* __restrict__ Mout, int M) {
  __shared__ u16 sA[128 * 64];
  __shared__ u16 sB[64 * 64];
  __shared__ u16 sA2[128 * 64];
  __shared__ u16 sB2[64 * 64];
  const int tid = threadIdx.x;
  const int l = tid & 63;
  const int w = tid >> 6;
  const int wm = w >> 1, wn = w & 1;
  const int row0 = blockIdx.x * 128;
  const int lc = l & 15;
  const int koff = (l >> 4) * 8;
  const int srl = l >> 3, ssl = l & 7;

  // async staging of A (hin rows) and B/B2 weights
#pragma unroll
  for (int c = 0; c < 4; ++c) {
    const int r = c * 32 + w * 8 + srl;
    const int gr = min(row0 + r, M - 1);
    const int gk = (ssl ^ (r & 7)) << 3;
    gload16(&A[(size_t)gr * 64 + gk], &sA[(c * 32 + w * 8) * 64]);
  }
#pragma unroll
  for (int c = 0; c < 2; ++c) {
    const int r = c * 32 + w * 8 + srl;
    const int gk = (ssl ^ (r & 7)) << 3;
    gload16(&B[(size_t)r * 64 + gk], &sB[(c * 32 + w * 8) * 64]);
    gload16(&B2[(size_t)r * 64 + gk], &sB2[(c * 32 + w * 8) * 64]);
  }
  // in-kernel gather: agg rows -> swizzled sA2 (8 lanes/node, uint4/lane)
  {
    const int gl = tid & 7;
    const int gn = tid >> 3;
#pragma unroll
    for (int p = 0; p < 4; ++p) {
      const int r = p * 32 + gn;
      const int v = row0 + r;
      uint4 mx = make_uint4(0u, 0u, 0u, 0u);
      if (v < M) {
        const int base = rp[v];
        const int dg = rp[v + 1] - base;
        mx = gather_row(magg, csr, base, dg, gl);
      }
      *(uint4*)&sA2[r * 64 + ((gl ^ (r & 7)) << 3)] = mx;
    }
  }
  __syncthreads();

  f32x4 acc[4][2];
#pragma unroll
  for (int mf = 0; mf < 4; ++mf)
#pragma unroll
    for (int nf = 0; nf < 2; ++nf) acc[mf][nf] = f32x4{0.f, 0.f, 0.f, 0.f};
#pragma unroll
  for (int kk = 0; kk < 2; ++kk) {
    short8 af[4], bfr[2], af2[4], bf2[2];
#pragma unroll
    for (int mf = 0; mf < 4; ++mf) {
      const int r = wm * 64 + mf * 16 + lc;
      const int sl = kk * 4 + (l >> 4);
      const int idx = r * 64 + ((sl ^ (r & 7)) << 3);
      af[mf] = *(const short8*)&sA[idx];
      af2[mf] = *(const short8*)&sA2[idx];
    }
#pragma unroll
    for (int nf = 0; nf < 2; ++nf) {
      const int r = wn * 32 + nf * 16 + lc;
      const int sl = kk * 4 + (l >> 4);
      const int idx = r * 64 + ((sl ^ (r & 7)) << 3);
      bfr[nf] = *(const short8*)&sB[idx];
      bf2[nf] = *(const short8*)&sB2[idx];
    }
#pragma unroll
    for (int mf = 0; mf < 4; ++mf)
#pragma unroll
      for (int nf = 0; nf < 2; ++nf) {
        acc[mf][nf] = __builtin_amdgcn_mfma_f32_16x16x32_bf16(
            af[mf], bfr[nf], acc[mf][nf], 0, 0, 0);
        acc[mf][nf] = __builtin_amdgcn_mfma_f32_16x16x32_bf16(
            af2[mf], bf2[nf], acc[mf][nf], 0, 0, 0);
      }
  }
  __syncthreads();

  const int lj = l >> 4;
#pragma unroll
  for (int mf = 0; mf < 4; ++mf)
#pragma unroll
    for (int nf = 0; nf < 2; ++nf) {
      const int col = wn * 32 + nf * 16 + lc;
      const float sh = bias[col];
#pragma unroll
      for (int j = 0; j < 4; ++j) {
        const int r = wm * 64 + mf * 16 + lj * 4 + j;
        const u16 hv = f2bf(fmaxf(acc[mf][nf][j] + sh, 0.f));
        sA[r * 64 + ((((col >> 3) ^ (r & 7)) << 3) | (col & 7))] = hv;
        const int row = row0 + r;
        if (row < M) Hout[(size_t)row * 64 + col] = hv;
      }
    }
  __syncthreads();

  f32x4 acc2[4][2];
#pragma unroll
  for (int mf = 0; mf < 4; ++mf)
#pragma unroll
    for (int nf = 0; nf < 2; ++nf) acc2[mf][nf] = f32x4{0.f, 0.f, 0.f, 0.f};
#pragma unroll
  for (int kk = 0; kk < 2; ++kk) {
    short8 af[4], bf[2];
#pragma unroll
    for (int mf = 0; mf < 4; ++mf) {
      const int r = wm * 64 + mf * 16 + lc;
      const int sl = kk * 4 + (l >> 4);
      af[mf] = *(const short8*)&sA[r * 64 + ((sl ^ (r & 7)) << 3)];
    }
#pragma unroll
    for (int nf = 0; nf < 2; ++nf)
      bf[nf] = *(const short8*)&Wp[(size_t)(wn * 32 + nf * 16 + lc) * 64 +
                                   kk * 32 + koff];
#pragma unroll
    for (int mf = 0; mf < 4; ++mf)
#pragma unroll
      for (int nf = 0; nf < 2; ++nf)
        acc2[mf][nf] = __builtin_amdgcn_mfma_f32_16x16x32_bf16(
            af[mf], bf[nf], acc2[mf][nf], 0, 0, 0);
  }
#pragma unroll
  for (int mf = 0; mf < 4; ++mf)
#pragma unroll
    for (int nf = 0; nf < 2; ++nf) {
      const int col = wn * 32 + nf * 16 + lc;
      const float sh = bp[col];
#pragma unroll
      for (int j = 0; j < 4; ++j) {
        const int row = row0 + wm * 64 + mf * 16 + lj * 4 + j;
        if (row < M)
          Mout[(size_t)row * 64 + col] = f2bf(fmaxf(acc2[mf][nf][j] + sh, 0.f));
      }
    }
}

// ---------------------------------------------------------------------------
// Final layer with in-kernel gather: C[N,8] = h2@Ws^T + agg@Wn^T + b (fp32).
// Computes 64 cols, stores cols < 8. Accumulation order matches round-23.
// ---------------------------------------------------------------------------
__global__ __launch_bounds__(256) void final_g(
    const u16* __restrict__ A, const u16* __restrict__ magg,
    const int* __restrict__ csr, const int* __restrict__ rp,
    const u16* __restrict__ B, const u16* __restrict__ B2,
    const float* __restrict__ bias, float* __restrict__ C, int M) {
  __shared__ u16 sA[128 * 64];
  __shared__ u16 sB[64 * 64];
  __shared__ u16 sA2[128 * 64];
  __shared__ u16 sB2[64 * 64];
  const int tid = threadIdx.x;
  const int l = tid & 63;
  const int w = tid >> 6;
  const int wm = w >> 1, wn = w & 1;
  const int row0 = blockIdx.x * 128;
  const int lc = l & 15;
  const int srl = l >> 3, ssl = l & 7;

#pragma unroll
  for (int c = 0; c < 4; ++c) {
    const int r = c * 32 + w * 8 + srl;
    const int gr = min(row0 + r, M - 1);
    const int gk = (ssl ^ (r & 7)) << 3;
    gload16(&A[(size_t)gr * 64 + gk], &sA[(c * 32 + w * 8) * 64]);
  }
#pragma unroll
  for (int c = 0; c < 2; ++c) {
    const int r = c * 32 + w * 8 + srl;
    const int gr = min(r, 7);  // Nout = 8
    const int gk = (ssl ^ (r & 7)) << 3;
    gload16(&B[(size_t)gr * 64 + gk], &sB[(c * 32 + w * 8) * 64]);
    gload16(&B2[(size_t)gr * 64 + gk], &sB2[(c * 32 + w * 8) * 64]);
  }
  {
    const int gl = tid & 7;
    const int gn = tid >> 3;
#pragma unroll
    for (int p = 0; p < 4; ++p) {
      const int r = p * 32 + gn;
      const int v = row0 + r;
      uint4 mx = make_uint4(0u, 0u, 0u, 0u);
      if (v < M) {
        const int base = rp[v];
        const int dg = rp[v + 1] - base;
        mx = gather_row(magg, csr, base, dg, gl);
      }
      *(uint4*)&sA2[r * 64 + ((gl ^ (r & 7)) << 3)] = mx;
    }
  }
  __syncthreads();

  f32x4 acc[4][2];
#pragma unroll
  for (int mf = 0; mf < 4; ++mf)
#pragma unroll
    for (int nf = 0; nf < 2; ++nf) acc[mf][nf] = f32x4{0.f, 0.f, 0.f, 0.f};
#pragma unroll
  for (int kk = 0; kk < 2; ++kk) {
    short8 af[4], bfr[2], af2[4], bf2[2];
#pragma unroll
    for (int mf = 0; mf < 4; ++mf) {
      const int r = wm * 64 + mf * 16 + lc;
      const int sl = kk * 4 + (l >> 4);
      const int idx = r * 64 + ((sl ^ (r & 7)) << 3);
      af[mf] = *(const short8*)&sA[idx];
      af2[mf] = *(const short8*)&sA2[idx];
    }
#pragma unroll
    for (int nf = 0; nf < 2; ++nf) {
      const int r = wn * 32 + nf * 16 + lc;
      const int sl = kk * 4 + (l >> 4);
      const int idx = r * 64 + ((sl ^ (r & 7)) << 3);
      bfr[nf] = *(const short8*)&sB[idx];
      bf2[nf] = *(const short8*)&sB2[idx];
    }
#pragma unroll
    for (int mf = 0; mf < 4; ++mf)
#pragma unroll
      for (int nf = 0; nf < 2; ++nf) {
        acc[mf][nf] = __builtin_amdgcn_mfma_f32_16x16x32_bf16(
            af[mf], bfr[nf], acc[mf][nf], 0, 0, 0);
        acc[mf][nf] = __builtin_amdgcn_mfma_f32_16x16x32_bf16(
            af2[mf], bf2[nf], acc[mf][nf], 0, 0, 0);
      }
  }

  const int lj = l >> 4;
#pragma unroll
  for (int mf = 0; mf < 4; ++mf)
#pragma unroll
    for (int nf = 0; nf < 2; ++nf) {
      const int col = wn * 32 + nf * 16 + lc;
      if (col >= 8) continue;
      const float sh = bias[col];
#pragma unroll
      for (int j = 0; j < 4; ++j) {
        const int row = row0 + wm * 64 + mf * 16 + lj * 4 + j;
        if (row < M) C[(size_t)row * 8 + col] = acc[mf][nf][j] + sh;
      }
    }
}

// ---- merged fp32->bf16 weight conversion (sage weights) ----
struct WConv {
  const float* src[9];
  u16* dst[9];
  int n[9];
};
__global__ __launch_bounds__(256) void wconv_k(WConv wc) {
  const int t = blockIdx.y;
  const float* in = wc.src[t];
  u16* out = wc.dst[t];
  const int n = wc.n[t];
  const int stride4 = gridDim.x * blockDim.x * 4;
  for (int i4 = (blockIdx.x * blockDim.x + threadIdx.x) * 4; i4 < n; i4 += stride4) {
    float4 f = *(const float4*)&in[i4];
    ushort4 o;
    o.x = f2bf(f.x); o.y = f2bf(f.y); o.z = f2bf(f.z); o.w = f2bf(f.w);
    *(ushort4*)&out[i4] = o;
  }
}

// fp32 combined layer2(Linear+BN)+decoder weight [64,500] (0.5 folded) + cc
__global__ __launch_bounds__(256) void combine_wcf(
    const float* __restrict__ W2, const float* __restrict__ b2,
    const float* __restrict__ g2, const float* __restrict__ be2,
    const float* __restrict__ m2, const float* __restrict__ v2,
    const float* __restrict__ Wd, const float* __restrict__ bd,
    float* __restrict__ Wcf, float* __restrict__ cc) {
  const int o = blockIdx.y;
  const int k = blockIdx.x * 256 + threadIdx.x;
  __shared__ float t2[128];
  if (threadIdx.x < 128) {
    const int j = threadIdx.x;
    const float s = g2[j] * rsqrtf(v2[j] + EPSV);
    t2[j] = Wd[o * 128 + j] * s;
  }
  __syncthreads();
  if (k < 500) {
    float accv = 0.f;
    for (int j = 0; j < 128; ++j) accv += t2[j] * W2[j * 500 + k];
    Wcf[o * 500 + k] = 0.5f * accv;
  }
  if (blockIdx.x == 0 && threadIdx.x == 0) {
    float accv = bd[o];
    for (int j = 0; j < 128; ++j) {
      const float s = g2[j] * rsqrtf(v2[j] + EPSV);
      accv += Wd[o * 128 + j] * ((b2[j] - m2[j]) * s + be2[j]);
    }
    cc[o] = 0.5f * accv;
  }
}

// Parallel Weff (round-23 proven)
__global__ __launch_bounds__(256) void weff2_k(
    const float* __restrict__ Wcf, const float* __restrict__ cc,
    const float* __restrict__ g1, const float* __restrict__ be1,
    const float* __restrict__ b1, const float* __restrict__ m1,
    const float* __restrict__ v1, const float* __restrict__ W1, int D,
    u16* __restrict__ Weffb, float* __restrict__ beff) {
  const int o = blockIdx.y;
  const int t = threadIdx.x;
  __shared__ float wcs[500];
  __shared__ float psum[256];
  for (int j = t; j < 500; j += 256) {
    const float s = g1[j] * rsqrtf(v1[j] + EPSV);
    wcs[j] = Wcf[o * 500 + j] * s;
  }
  __syncthreads();
  const int dl = t & 63, jt = t >> 6;
  const int d = blockIdx.x * 64 + dl;
  const int j0 = jt * 125;
  float accv = 0.f;
  if (d < D) {
    for (int j = j0; j < j0 + 125; ++j) accv += wcs[j] * W1[(size_t)j * D + d];
  }
  psum[t] = accv;
  __syncthreads();
  if (jt == 0 && d < D) {
    const float tot = psum[dl] + psum[64 + dl] + psum[128 + dl] + psum[192 + dl];
    Weffb[o * D + d] = f2bf(tot);
  }
  if (blockIdx.x == 0) {
    __syncthreads();
    float pb = 0.f;
    for (int j = t; j < 500; j += 256) {
      const float s = g1[j] * rsqrtf(v1[j] + EPSV);
      pb += Wcf[o * 500 + j] * ((b1[j] - m1[j]) * s + be1[j]);
    }
    psum[t] = pb;
    __syncthreads();
    for (int off2 = 128; off2 > 0; off2 >>= 1) {
      if (t < off2) psum[t] += psum[t + off2];
      __syncthreads();
    }
    if (t == 0) beff[o] = psum[0] + cc[o];
  }
}

// ---------------------------------------------------------------------------
// Bucket-sorted CSR build, block-privatized (round-11 proven).
// ---------------------------------------------------------------------------
__global__ __launch_bounds__(256) void bhist_k(const int* __restrict__ dst,
                                               int* __restrict__ bhist, int ne,
                                               int nbuck, int epb) {
  __shared__ int cnt[NBUCK_C];
  const int t = threadIdx.x;
  for (int i = t; i < nbuck; i += 256) cnt[i] = 0;
  __syncthreads();
  const int e0 = blockIdx.x * epb;
  const int e1 = min(e0 + epb, ne);
  for (int i = e0 + t; i < e1; i += 256) atomicAdd(&cnt[dst[i] >> 8], 1);
  __syncthreads();
  for (int i = t; i < nbuck; i += 256) {
    const int c = cnt[i];
    if (c) atomicAdd(&bhist[i], c);
  }
}

__global__ __launch_bounds__(512) void bscan_k(const int* __restrict__ bhist,
                                               int* __restrict__ base,
                                               int* __restrict__ cursor,
                                               int nbuck, int ne) {
  __shared__ int lds[512];
  const int t = threadIdx.x;
  const int v = t < nbuck ? bhist[t] : 0;
  lds[t] = v;
  __syncthreads();
  for (int o = 1; o < 512; o <<= 1) {
    const int u = t >= o ? lds[t - o] : 0;
    __syncthreads();
    lds[t] += u;
    __syncthreads();
  }
  if (t < nbuck) {
    const int ex = lds[t] - v;
    base[t] = ex;
    cursor[t] = ex;
  }
  if (t == 0) base[nbuck] = ne;
}

__global__ __launch_bounds__(256) void bscat_k(const int* __restrict__ src,
                                               const int* __restrict__ dst,
                                               int* __restrict__ cursor,
                                               u32* __restrict__ tmp, int ne,
                                               int nbuck, int epb) {
  __shared__ int cnt[NBUCK_C];
  __shared__ int gbase[NBUCK_C];
  const int t = threadIdx.x;
  for (int i = t; i < nbuck; i += 256) cnt[i] = 0;
  __syncthreads();
  const int e0 = blockIdx.x * epb;
  const int e1 = min(e0 + epb, ne);
  for (int i = e0 + t; i < e1; i += 256) atomicAdd(&cnt[dst[i] >> 8], 1);
  __syncthreads();
  for (int i = t; i < nbuck; i += 256) {
    const int c = cnt[i];
    gbase[i] = c ? atomicAdd(&cursor[i], c) : 0;
    cnt[i] = 0;
  }
  __syncthreads();
  for (int i = e0 + t; i < e1; i += 256) {
    const int d = dst[i];
    const int b = d >> 8;
    const int p = atomicAdd(&cnt[b], 1);
    tmp[gbase[b] + p] = ((u32)src[i] << 8) | (u32)(d & 255);
  }
}

__global__ __launch_bounds__(256) void bsort_k(const u32* __restrict__ tmp,
                                               const int* __restrict__ base,
                                               int* __restrict__ rp,
                                               int* __restrict__ csr, int n) {
  const int b = blockIdx.x;
  const int t = threadIdx.x;
  __shared__ int cnt[256];
  __shared__ int loc[256];
  const int segbase = base[b];
  const int len = base[b + 1] - segbase;
  cnt[t] = 0;
  __syncthreads();
  for (int i = t; i < len; i += 256) atomicAdd(&cnt[tmp[segbase + i] & 255], 1);
  __syncthreads();
  const int own = cnt[t];
  __syncthreads();
  for (int o = 1; o < 256; o <<= 1) {
    const int u = t >= o ? cnt[t - o] : 0;
    __syncthreads();
    cnt[t] += u;
    __syncthreads();
  }
  const int pre = cnt[t] - own;
  loc[t] = pre;
  const int gnode = b * 256 + t;
  if (gnode <= n) rp[gnode] = segbase + pre;  // includes rp[N]=NE sentinel
  __syncthreads();
  for (int i = t; i < len; i += 256) {
    const u32 v = tmp[segbase + i];
    const int p = atomicAdd(&loc[v & 255], 1);
    csr[segbase + p] = (int)(v >> 8);
  }
}

extern "C" void kernel_launch(void* const* d_in, const int* in_sizes, int n_in,
                              void* d_out, int out_size, void* d_ws,
                              size_t ws_size, hipStream_t stream) {
  const int N = 100000;
  const int NE = in_sizes[2];
  const float* x0 = (const float*)d_in[0];
  const float* x1 = (const float*)d_in[1];
  const int* src = (const int*)d_in[2];
  const int* dst = (const int*)d_in[3];
  auto F = [&](int i) { return (const float*)d_in[i]; };

  char* wsb = (char*)d_ws;
  size_t off = 0;
  auto alloc = [&](size_t bytes) {
    void* p = wsb + off;
    off += (bytes + 255) & ~(size_t)255;
    return p;
  };
  float* Wcf0 = (float*)alloc(64 * 500 * 4);
  float* Wcf1 = (float*)alloc(64 * 500 * 4);
  float* cc0 = (float*)alloc(64 * 4);
  float* cc1 = (float*)alloc(64 * 4);
  u16* Weff0b = (u16*)alloc(64 * 512 * 2);
  u16* Weff1b = (u16*)alloc(64 * 256 * 2);
  float* beff0 = (float*)alloc(64 * 4);
  float* beff1 = (float*)alloc(64 * 4);
  u16* swb[9];
  const int swsrc[9] = {32, 34, 35, 37, 39, 40, 42, 44, 45};
  const int swn[9] = {4096, 4096, 4096, 4096, 4096, 4096, 4096, 512, 512};
  for (int i = 0; i < 9; ++i) swb[i] = (u16*)alloc(swn[i] * 2);
  u16* featb = (u16*)alloc((size_t)N * 64 * 2);
  u16* mb0 = (u16*)alloc((size_t)N * 64 * 2);
  u16* mb1 = (u16*)alloc((size_t)N * 64 * 2);
  u16* h1b = (u16*)alloc((size_t)N * 64 * 2);
  u16* h2b = (u16*)alloc((size_t)N * 64 * 2);
  const int NBUCK = (N + 255) / 256;  // 391 < NBUCK_C
  int* rp = (int*)alloc((size_t)(N + 1) * 4);
  int* csr = (int*)alloc((size_t)NE * 4);
  u32* tmp = (u32*)alloc((size_t)NE * 4);
  int* bhist = (int*)alloc((size_t)NBUCK * 4);
  int* base = (int*)alloc((size_t)(NBUCK + 1) * 4);
  int* cursor = (int*)alloc((size_t)NBUCK * 4);
  (void)n_in; (void)ws_size;

  // weight prep
  WConv wc;
  for (int i = 0; i < 9; ++i) {
    wc.src[i] = F(swsrc[i]); wc.dst[i] = swb[i]; wc.n[i] = swn[i];
  }
  wconv_k<<<dim3(8, 9), 256, 0, stream>>>(wc);
  combine_wcf<<<dim3(2, 64), 256, 0, stream>>>(F(10), F(11), F(12), F(13),
                                               F(14), F(15), F(16), F(17),
                                               Wcf0, cc0);
  combine_wcf<<<dim3(2, 64), 256, 0, stream>>>(F(24), F(25), F(26), F(27),
                                               F(28), F(29), F(30), F(31),
                                               Wcf1, cc1);
  weff2_k<<<dim3(8, 64), 256, 0, stream>>>(Wcf0, cc0, F(6), F(7), F(5), F(8),
                                           F(9), F(4), 512, Weff0b, beff0);
  weff2_k<<<dim3(4, 64), 256, 0, stream>>>(Wcf1, cc1, F(20), F(21), F(19),
                                           F(22), F(23), F(18), 256, Weff1b,
                                           beff1);

  // bucket-sorted CSR build (block-privatized histogram + scatter)
  const int NSB = 512;
  const int EPB = (NE + NSB - 1) / NSB;
  hipMemsetAsync(bhist, 0, (size_t)NBUCK * 4, stream);
  bhist_k<<<NSB, 256, 0, stream>>>(dst, bhist, NE, NBUCK, EPB);
  bscan_k<<<1, 512, 0, stream>>>(bhist, base, cursor, NBUCK, NE);
  bscat_k<<<NSB, 256, 0, stream>>>(src, dst, cursor, tmp, NE, NBUCK, EPB);
  bsort_k<<<NBUCK, 256, 0, stream>>>(tmp, base, rp, csr, N);

  // encoder + fused layer-0 pool (BM=64, all-reg-staged) -> featb, mb0
  enc_fused64<<<(N + 63) / 64, 256, 0, stream>>>(x0, x1, Weff0b, Weff1b,
                                                 beff0, beff1, swb[0], F(33),
                                                 featb, mb0, N);

  const int gx = (N + 127) / 128;
  // layer 0: gather(mb0) in-kernel; h1 + layer-1 pool -> mb1
  sage_g_fused<<<gx, 256, 0, stream>>>(featb, mb0, csr, rp, swb[1], swb[2],
                                       F(36), swb[3], F(38), h1b, mb1, N);
  // layer 1: gather(mb1) in-kernel; h2 + layer-2 pool -> mb0
  sage_g_fused<<<gx, 256, 0, stream>>>(h1b, mb1, csr, rp, swb[4], swb[5],
                                       F(41), swb[6], F(43), h2b, mb0, N);
  // layer 2: gather(mb0) in-kernel; final fp32 out
  final_g<<<gx, 256, 0, stream>>>(h2b, mb0, csr, rp, swb[7], swb[8], F(46),
                                  (float*)d_out, N);
  (void)out_size;
}

// Round 25
// 340.548 us; speedup vs baseline: 1.1387x; 1.1387x over previous
//
#include <hip/hip_runtime.h>
#include <hip/hip_bf16.h>

#define EPSV 1e-5f
#define NBUCK_C 400
using u16 = unsigned short;
using u32 = unsigned int;
typedef __attribute__((ext_vector_type(8))) short short8;
typedef __attribute__((ext_vector_type(4))) float f32x4;

__device__ __forceinline__ u16 f2bf(float f) {
  __hip_bfloat16 h = __float2bfloat16(f);
  u16 u; __builtin_memcpy(&u, &h, 2); return u;
}

__device__ __forceinline__ void gload16(const void* g, void* l) {
  __builtin_amdgcn_global_load_lds(
      (const __attribute__((address_space(1))) void*)g,
      (__attribute__((address_space(3))) void*)l, 16, 0, 0);
}

// packed 2x u16 max (bf16 >= 0 orders as u16; mask-compare per half)
__device__ __forceinline__ u32 mx2(u32 a, u32 b) {
  u32 ah = a & 0xFFFF0000u, bh = b & 0xFFFF0000u;
  u32 al = a & 0x0000FFFFu, bl = b & 0x0000FFFFu;
  return (ah > bh ? ah : bh) | (al > bl ? al : bl);
}
__device__ __forceinline__ uint4 mx4(uint4 a, uint4 b) {
  return make_uint4(mx2(a.x, b.x), mx2(a.y, b.y), mx2(a.z, b.z), mx2(a.w, b.w));
}

// ---------------------------------------------------------------------------
// Collapsed encoder + fused layer-0 pool, BM=64 all-reg-staged (latency floor
// declared; do not touch).
// ---------------------------------------------------------------------------
struct EncR { float4 a[4]; short8 b[2]; };

__global__ __launch_bounds__(256) void enc_fused64(
    const float* __restrict__ x0, const float* __restrict__ x1,
    const u16* __restrict__ W0, const u16* __restrict__ W1,
    const float* __restrict__ beff0, const float* __restrict__ beff1,
    const u16* __restrict__ Wp, const float* __restrict__ bp,
    u16* __restrict__ out, u16* __restrict__ mout, int M) {
  __shared__ u16 sA[64 * 64];
  __shared__ u16 sB[64 * 64];
  const int tid = threadIdx.x;
  const int l = tid & 63;
  const int w = tid >> 6;
  const int row0 = blockIdx.x * 64;
  const int lc = l & 15;
  const int koff = (l >> 4) * 8;

  f32x4 acc[4];
#pragma unroll
  for (int nf = 0; nf < 4; ++nf) acc[nf] = f32x4{0.f, 0.f, 0.f, 0.f};

  auto loadstep = [&](EncR& rs, int s) {
    const int ph = s >= 8;
    const float* X = ph ? x1 : x0;
    const u16* W = ph ? W1 : W0;
    const int lda = ph ? 256 : 512;
    const int kb = (s - (ph ? 8 : 0)) * 64;
#pragma unroll
    for (int c = 0; c < 2; ++c) {
      const int r = c * 32 + (tid >> 3);
      const int gr = min(row0 + r, M - 1);
      const float* gp = &X[(size_t)gr * lda + kb + ((tid & 7) << 3)];
      rs.a[c * 2] = *(const float4*)gp;
      rs.a[c * 2 + 1] = *(const float4*)(gp + 4);
    }
#pragma unroll
    for (int i = 0; i < 2; ++i) {
      const int s2 = tid * 2 + i;
      const int rb = s2 >> 3, sl = s2 & 7;
      rs.b[i] = *(const short8*)&W[rb * lda + kb + sl * 8];
    }
  };
  auto storestep = [&](const EncR& rs) {
#pragma unroll
    for (int c = 0; c < 2; ++c) {
      const int r = c * 32 + (tid >> 3);
      const int ssl = tid & 7;
      short8 pk;
#pragma unroll
      for (int j = 0; j < 4; ++j) pk[j] = (short)f2bf(rs.a[c * 2][j]);
#pragma unroll
      for (int j = 0; j < 4; ++j) pk[4 + j] = (short)f2bf(rs.a[c * 2 + 1][j]);
      *(short8*)&sA[r * 64 + ((ssl ^ (r & 7)) << 3)] = pk;
    }
#pragma unroll
    for (int i = 0; i < 2; ++i) {
      const int s2 = tid * 2 + i;
      const int rb = s2 >> 3, sl = s2 & 7;
      *(short8*)&sB[rb * 64 + ((sl ^ (rb & 7)) << 3)] = rs.b[i];
    }
  };
  auto compute = [&]() {
#pragma unroll
    for (int kk = 0; kk < 2; ++kk) {
      const int r = w * 16 + lc;
      const int sl = kk * 4 + (l >> 4);
      const short8 af = *(const short8*)&sA[r * 64 + ((sl ^ (r & 7)) << 3)];
#pragma unroll
      for (int nf = 0; nf < 4; ++nf) {
        const int rb = nf * 16 + lc;
        const short8 bf = *(const short8*)&sB[rb * 64 + ((sl ^ (rb & 7)) << 3)];
        acc[nf] = __builtin_amdgcn_mfma_f32_16x16x32_bf16(af, bf, acc[nf], 0, 0, 0);
      }
    }
  };

  EncR rA, rB;
  loadstep(rA, 0);
  for (int s = 0; s < 12; s += 2) {
    loadstep(rB, s + 1);
    storestep(rA);
    __syncthreads();
    compute();
    __syncthreads();
    if (s + 2 < 12) loadstep(rA, s + 2);
    storestep(rB);
    __syncthreads();
    compute();
    __syncthreads();
  }

  // epilogue 1: feat -> global + LDS restage (bf16, swizzled element layout)
  const int lj = l >> 4;
#pragma unroll
  for (int nf = 0; nf < 4; ++nf) {
    const int col = nf * 16 + lc;
    const float sh = beff0[col] + beff1[col];
#pragma unroll
    for (int j = 0; j < 4; ++j) {
      const int r = w * 16 + lj * 4 + j;
      const u16 hv = f2bf(acc[nf][j] + sh);
      sA[r * 64 + ((((col >> 3) ^ (r & 7)) << 3) | (col & 7))] = hv;
      const int row = row0 + r;
      if (row < M) out[(size_t)row * 64 + col] = hv;
    }
  }
  __syncthreads();

  // pool: m = relu(feat @ Wp^T + bp)
  f32x4 acc2[4];
#pragma unroll
  for (int nf = 0; nf < 4; ++nf) acc2[nf] = f32x4{0.f, 0.f, 0.f, 0.f};
#pragma unroll
  for (int kk = 0; kk < 2; ++kk) {
    const int r = w * 16 + lc;
    const int sl = kk * 4 + (l >> 4);
    const short8 af = *(const short8*)&sA[r * 64 + ((sl ^ (r & 7)) << 3)];
#pragma unroll
    for (int nf = 0; nf < 4; ++nf) {
      const short8 bf =
          *(const short8*)&Wp[(size_t)(nf * 16 + lc) * 64 + kk * 32 + koff];
      acc2[nf] = __builtin_amdgcn_mfma_f32_16x16x32_bf16(af, bf, acc2[nf], 0, 0, 0);
    }
  }
#pragma unroll
  for (int nf = 0; nf < 4; ++nf) {
    const int col = nf * 16 + lc;
    const float sh = bp[col];
#pragma unroll
    for (int j = 0; j < 4; ++j) {
      const int row = row0 + w * 16 + lj * 4 + j;
      if (row < M)
        mout[(size_t)row * 64 + col] = f2bf(fmaxf(acc2[nf][j] + sh, 0.f));
    }
  }
}

// ---------------------------------------------------------------------------
// Fused SAGE layer (round-15 proven): h = relu(A@Ws^T + A2@Wn^T + b) -> Hout,
// then next layer's pool m = relu(h @ Wp^T + bp) -> Mout. K=64, BM=128.
// ---------------------------------------------------------------------------
__global__ __launch_bounds__(256) void sage_fused(
    const u16* __restrict__ A, const u16* __restrict__ A2,
    const u16* __restrict__ B, const u16* __restrict__ B2,
    const float* __restrict__ bias, const u16* __restrict__ Wp,
    const float* __restrict__ bp, u16* __restrict__ Hout,
    u16* __restrict__ Mout, int M) {
  __shared__ u16 sA[128 * 64];
  __shared__ u16 sB[64 * 64];
  __shared__ u16 sA2[128 * 64];
  __shared__ u16 sB2[64 * 64];
  const int tid = threadIdx.x;
  const int l = tid & 63;
  const int w = tid >> 6;
  const int wm = w >> 1, wn = w & 1;
  const int row0 = blockIdx.x * 128;
  const int lc = l & 15;
  const int koff = (l >> 4) * 8;
  const int srl = l >> 3, ssl = l & 7;

  f32x4 acc[4][2];
#pragma unroll
  for (int mf = 0; mf < 4; ++mf)
#pragma unroll
    for (int nf = 0; nf < 2; ++nf) acc[mf][nf] = f32x4{0.f, 0.f, 0.f, 0.f};

#pragma unroll
  for (int c = 0; c < 4; ++c) {
    const int r = c * 32 + w * 8 + srl;
    const int gr = min(row0 + r, M - 1);
    const int gk = (ssl ^ (r & 7)) << 3;
    gload16(&A[(size_t)gr * 64 + gk], &sA[(c * 32 + w * 8) * 64]);
    gload16(&A2[(size_t)gr * 64 + gk], &sA2[(c * 32 + w * 8) * 64]);
  }
#pragma unroll
  for (int c = 0; c < 2; ++c) {
    const int r = c * 32 + w * 8 + srl;
    const int gk = (ssl ^ (r & 7)) << 3;
    gload16(&B[(size_t)r * 64 + gk], &sB[(c * 32 + w * 8) * 64]);
    gload16(&B2[(size_t)r * 64 + gk], &sB2[(c * 32 + w * 8) * 64]);
  }
  __syncthreads();
#pragma unroll
  for (int kk = 0; kk < 2; ++kk) {
    short8 af[4], bfr[2], af2[4], bf2[2];
#pragma unroll
    for (int mf = 0; mf < 4; ++mf) {
      const int r = wm * 64 + mf * 16 + lc;
      const int sl = kk * 4 + (l >> 4);
      const int idx = r * 64 + ((sl ^ (r & 7)) << 3);
      af[mf] = *(const short8*)&sA[idx];
      af2[mf] = *(const short8*)&sA2[idx];
    }
#pragma unroll
    for (int nf = 0; nf < 2; ++nf) {
      const int r = wn * 32 + nf * 16 + lc;
      const int sl = kk * 4 + (l >> 4);
      const int idx = r * 64 + ((sl ^ (r & 7)) << 3);
      bfr[nf] = *(const short8*)&sB[idx];
      bf2[nf] = *(const short8*)&sB2[idx];
    }
#pragma unroll
    for (int mf = 0; mf < 4; ++mf)
#pragma unroll
      for (int nf = 0; nf < 2; ++nf) {
        acc[mf][nf] = __builtin_amdgcn_mfma_f32_16x16x32_bf16(
            af[mf], bfr[nf], acc[mf][nf], 0, 0, 0);
        acc[mf][nf] = __builtin_amdgcn_mfma_f32_16x16x32_bf16(
            af2[mf], bf2[nf], acc[mf][nf], 0, 0, 0);
      }
  }
  __syncthreads();

  const int lj = l >> 4;
#pragma unroll
  for (int mf = 0; mf < 4; ++mf)
#pragma unroll
    for (int nf = 0; nf < 2; ++nf) {
      const int col = wn * 32 + nf * 16 + lc;
      const float sh = bias[col];
#pragma unroll
      for (int j = 0; j < 4; ++j) {
        const int r = wm * 64 + mf * 16 + lj * 4 + j;
        const u16 hv = f2bf(fmaxf(acc[mf][nf][j] + sh, 0.f));
        sA[r * 64 + ((((col >> 3) ^ (r & 7)) << 3) | (col & 7))] = hv;
        const int row = row0 + r;
        if (row < M) Hout[(size_t)row * 64 + col] = hv;
      }
    }
  __syncthreads();

  f32x4 acc2[4][2];
#pragma unroll
  for (int mf = 0; mf < 4; ++mf)
#pragma unroll
    for (int nf = 0; nf < 2; ++nf) acc2[mf][nf] = f32x4{0.f, 0.f, 0.f, 0.f};
#pragma unroll
  for (int kk = 0; kk < 2; ++kk) {
    short8 af[4], bf[2];
#pragma unroll
    for (int mf = 0; mf < 4; ++mf) {
      const int r = wm * 64 + mf * 16 + lc;
      const int sl = kk * 4 + (l >> 4);
      af[mf] = *(const short8*)&sA[r * 64 + ((sl ^ (r & 7)) << 3)];
    }
#pragma unroll
    for (int nf = 0; nf < 2; ++nf)
      bf[nf] = *(const short8*)&Wp[(size_t)(wn * 32 + nf * 16 + lc) * 64 +
                                   kk * 32 + koff];
#pragma unroll
    for (int mf = 0; mf < 4; ++mf)
#pragma unroll
      for (int nf = 0; nf < 2; ++nf)
        acc2[mf][nf] = __builtin_amdgcn_mfma_f32_16x16x32_bf16(
            af[mf], bf[nf], acc2[mf][nf], 0, 0, 0);
  }
#pragma unroll
  for (int mf = 0; mf < 4; ++mf)
#pragma unroll
    for (int nf = 0; nf < 2; ++nf) {
      const int col = wn * 32 + nf * 16 + lc;
      const float sh = bp[col];
#pragma unroll
      for (int j = 0; j < 4; ++j) {
        const int row = row0 + wm * 64 + mf * 16 + lj * 4 + j;
        if (row < M)
          Mout[(size_t)row * 64 + col] = f2bf(fmaxf(acc2[mf][nf][j] + sh, 0.f));
      }
    }
}

// ---------------------------------------------------------------------------
// bf16 MFMA NT GEMM (final layer only) — round-11 proven kernel.
// ---------------------------------------------------------------------------
template <int BN, int EPI, bool DUAL, bool AF32, bool BIAS2, typename OUT>
__global__ __launch_bounds__(256) void gemm_mfma(
    const void* __restrict__ A, int lda, const u16* __restrict__ B, int ldb,
    const u16* __restrict__ A2, const u16* __restrict__ B2, void* __restrict__ C,
    int ldc, int M, int Nout, int K, int storeN, int nby,
    const float* __restrict__ bias, const float* __restrict__ bnb,
    const float* __restrict__ bng, const float* __restrict__ bnbe,
    const float* __restrict__ bnm, const float* __restrict__ bnv) {
  constexpr int WN = BN / 2;
  constexpr int NF = WN / 16;
  constexpr int MF = 4;
  __shared__ u16 sA[128 * 64];
  __shared__ u16 sB[BN * 64];
  __shared__ u16 sA2[DUAL ? 128 * 64 : 8];
  __shared__ u16 sB2[DUAL ? BN * 64 : 8];

  const int nb = gridDim.x;
  const int orig = blockIdx.x;
  const int q = nb >> 3, rr = nb & 7;
  const int xcd = orig & 7, idx = orig >> 3;
  const int wg = (xcd < rr ? xcd * (q + 1) : rr * (q + 1) + (xcd - rr) * q) + idx;
  const int bx = wg / nby;
  const int by = wg % nby;

  const int tid = threadIdx.x;
  const int l = tid & 63;
  const int w = tid >> 6;
  const int wm = w >> 1, wn = w & 1;
  const int row0 = bx * 128;
  const int col0 = by * BN;

  f32x4 acc[MF][NF];
#pragma unroll
  for (int mf = 0; mf < MF; ++mf)
#pragma unroll
    for (int nf = 0; nf < NF; ++nf) acc[mf][nf] = f32x4{0.f, 0.f, 0.f, 0.f};

  const int srl = l >> 3;
  const int ssl = l & 7;
  const u16* Ab = (const u16*)A;
  const float* Af = (const float*)A;

  const int ksteps = K >> 6;
  for (int kt = 0; kt < ksteps; ++kt) {
    const int kb = kt * 64;
    if constexpr (AF32) {
      const int ssl2 = tid & 7;
#pragma unroll
      for (int c = 0; c < 4; ++c) {
        const int r = c * 32 + (tid >> 3);
        const int gr = min(row0 + r, M - 1);
        const float* gp = &Af[(size_t)gr * lda + kb + (ssl2 << 3)];
        float4 f0 = *(const float4*)gp;
        float4 f1 = *(const float4*)(gp + 4);
        short8 pk;
        pk[0] = (short)f2bf(f0.x); pk[1] = (short)f2bf(f0.y);
        pk[2] = (short)f2bf(f0.z); pk[3] = (short)f2bf(f0.w);
        pk[4] = (short)f2bf(f1.x); pk[5] = (short)f2bf(f1.y);
        pk[6] = (short)f2bf(f1.z); pk[7] = (short)f2bf(f1.w);
        *(short8*)&sA[r * 64 + ((ssl2 ^ (r & 7)) << 3)] = pk;
      }
    } else {
#pragma unroll
      for (int c = 0; c < 4; ++c) {
        const int r = c * 32 + w * 8 + srl;
        const int gr = min(row0 + r, M - 1);
        const int gk = kb + ((ssl ^ (r & 7)) << 3);
        gload16(&Ab[(size_t)gr * lda + gk], &sA[(c * 32 + w * 8) * 64]);
        if (DUAL) gload16(&A2[(size_t)gr * lda + gk], &sA2[(c * 32 + w * 8) * 64]);
      }
    }
#pragma unroll
    for (int c = 0; c < BN / 32; ++c) {
      const int r = c * 32 + w * 8 + srl;
      const int gr = min(col0 + r, Nout - 1);
      const int gk = kb + ((ssl ^ (r & 7)) << 3);
      gload16(&B[(size_t)gr * ldb + gk], &sB[(c * 32 + w * 8) * 64]);
      if (DUAL) gload16(&B2[(size_t)gr * ldb + gk], &sB2[(c * 32 + w * 8) * 64]);
    }
    __syncthreads();
#pragma unroll
    for (int kk = 0; kk < 2; ++kk) {
      short8 af[MF], bfr[NF], af2[MF], bf2[NF];
#pragma unroll
      for (int mf = 0; mf < MF; ++mf) {
        const int r = wm * 64 + mf * 16 + (l & 15);
        const int sl = kk * 4 + (l >> 4);
        const int idx2 = r * 64 + ((sl ^ (r & 7)) << 3);
        af[mf] = *(const short8*)&sA[idx2];
        if (DUAL) af2[mf] = *(const short8*)&sA2[idx2];
      }
#pragma unroll
      for (int nf = 0; nf < NF; ++nf) {
        const int r = wn * WN + nf * 16 + (l & 15);
        const int sl = kk * 4 + (l >> 4);
        const int idx2 = r * 64 + ((sl ^ (r & 7)) << 3);
        bfr[nf] = *(const short8*)&sB[idx2];
        if (DUAL) bf2[nf] = *(const short8*)&sB2[idx2];
      }
#pragma unroll
      for (int mf = 0; mf < MF; ++mf)
#pragma unroll
        for (int nf = 0; nf < NF; ++nf) {
          acc[mf][nf] = __builtin_amdgcn_mfma_f32_16x16x32_bf16(
              af[mf], bfr[nf], acc[mf][nf], 0, 0, 0);
          if (DUAL)
            acc[mf][nf] = __builtin_amdgcn_mfma_f32_16x16x32_bf16(
                af2[mf], bf2[nf], acc[mf][nf], 0, 0, 0);
        }
    }
    __syncthreads();
  }

  const int lj = l >> 4;
  const int lc = l & 15;
#pragma unroll
  for (int mf = 0; mf < MF; ++mf)
#pragma unroll
    for (int nf = 0; nf < NF; ++nf) {
      const int col = col0 + wn * WN + nf * 16 + lc;
      if (col >= storeN) continue;
      const bool cok = col < Nout;
      float sc = 0.f, sh = 0.f;
      if (cok) {
        if (EPI == 2) {
          sc = bng[col] * rsqrtf(bnv[col] + EPSV);
          sh = (bnb[col] - bnm[col]) * sc + bnbe[col];
        } else {
          sh = bias[col];
          if (BIAS2) sh += bnb[col];
        }
      }
#pragma unroll
      for (int j = 0; j < 4; ++j) {
        const int row = row0 + wm * 64 + mf * 16 + lj * 4 + j;
        if (row >= M) continue;
        float v = 0.f;
        if (cok) {
          v = acc[mf][nf][j];
          if (EPI == 2) v = v * sc + sh;
          else { v += sh; if (EPI == 1) v = fmaxf(v, 0.f); }
        }
        const size_t idx2 = (size_t)row * ldc + col;
        if constexpr (sizeof(OUT) == 2) ((u16*)C)[idx2] = f2bf(v);
        else ((float*)C)[idx2] = v;
      }
    }
}

// ---- merged fp32->bf16 weight conversion (sage weights) ----
struct WConv {
  const float* src[9];
  u16* dst[9];
  int n[9];
};
__global__ __launch_bounds__(256) void wconv_k(WConv wc) {
  const int t = blockIdx.y;
  const float* in = wc.src[t];
  u16* out = wc.dst[t];
  const int n = wc.n[t];
  const int stride4 = gridDim.x * blockDim.x * 4;
  for (int i4 = (blockIdx.x * blockDim.x + threadIdx.x) * 4; i4 < n; i4 += stride4) {
    float4 f = *(const float4*)&in[i4];
    ushort4 o;
    o.x = f2bf(f.x); o.y = f2bf(f.y); o.z = f2bf(f.z); o.w = f2bf(f.w);
    *(ushort4*)&out[i4] = o;
  }
}

// fp32 combined layer2(Linear+BN)+decoder weight [64,500] (0.5 folded) + cc
__global__ __launch_bounds__(256) void combine_wcf(
    const float* __restrict__ W2, const float* __restrict__ b2,
    const float* __restrict__ g2, const float* __restrict__ be2,
    const float* __restrict__ m2, const float* __restrict__ v2,
    const float* __restrict__ Wd, const float* __restrict__ bd,
    float* __restrict__ Wcf, float* __restrict__ cc) {
  const int o = blockIdx.y;
  const int k = blockIdx.x * 256 + threadIdx.x;
  __shared__ float t2[128];
  if (threadIdx.x < 128) {
    const int j = threadIdx.x;
    const float s = g2[j] * rsqrtf(v2[j] + EPSV);
    t2[j] = Wd[o * 128 + j] * s;
  }
  __syncthreads();
  if (k < 500) {
    float accv = 0.f;
    for (int j = 0; j < 128; ++j) accv += t2[j] * W2[j * 500 + k];
    Wcf[o * 500 + k] = 0.5f * accv;
  }
  if (blockIdx.x == 0 && threadIdx.x == 0) {
    float accv = bd[o];
    for (int j = 0; j < 128; ++j) {
      const float s = g2[j] * rsqrtf(v2[j] + EPSV);
      accv += Wd[o * 128 + j] * ((b2[j] - m2[j]) * s + be2[j]);
    }
    cc[o] = 0.5f * accv;
  }
}

// Parallel Weff (round-23 proven)
__global__ __launch_bounds__(256) void weff2_k(
    const float* __restrict__ Wcf, const float* __restrict__ cc,
    const float* __restrict__ g1, const float* __restrict__ be1,
    const float* __restrict__ b1, const float* __restrict__ m1,
    const float* __restrict__ v1, const float* __restrict__ W1, int D,
    u16* __restrict__ Weffb, float* __restrict__ beff) {
  const int o = blockIdx.y;
  const int t = threadIdx.x;
  __shared__ float wcs[500];
  __shared__ float psum[256];
  for (int j = t; j < 500; j += 256) {
    const float s = g1[j] * rsqrtf(v1[j] + EPSV);
    wcs[j] = Wcf[o * 500 + j] * s;
  }
  __syncthreads();
  const int dl = t & 63, jt = t >> 6;
  const int d = blockIdx.x * 64 + dl;
  const int j0 = jt * 125;
  float accv = 0.f;
  if (d < D) {
    for (int j = j0; j < j0 + 125; ++j) accv += wcs[j] * W1[(size_t)j * D + d];
  }
  psum[t] = accv;
  __syncthreads();
  if (jt == 0 && d < D) {
    const float tot = psum[dl] + psum[64 + dl] + psum[128 + dl] + psum[192 + dl];
    Weffb[o * D + d] = f2bf(tot);
  }
  if (blockIdx.x == 0) {
    __syncthreads();
    float pb = 0.f;
    for (int j = t; j < 500; j += 256) {
      const float s = g1[j] * rsqrtf(v1[j] + EPSV);
      pb += Wcf[o * 500 + j] * ((b1[j] - m1[j]) * s + be1[j]);
    }
    psum[t] = pb;
    __syncthreads();
    for (int off2 = 128; off2 > 0; off2 >>= 1) {
      if (t < off2) psum[t] += psum[t + off2];
      __syncthreads();
    }
    if (t == 0) beff[o] = psum[0] + cc[o];
  }
}

// ---------------------------------------------------------------------------
// Bucket-sorted CSR build, block-privatized (round-11 proven).
// ---------------------------------------------------------------------------
__global__ __launch_bounds__(256) void bhist_k(const int* __restrict__ dst,
                                               int* __restrict__ bhist, int ne,
                                               int nbuck, int epb) {
  __shared__ int cnt[NBUCK_C];
  const int t = threadIdx.x;
  for (int i = t; i < nbuck; i += 256) cnt[i] = 0;
  __syncthreads();
  const int e0 = blockIdx.x * epb;
  const int e1 = min(e0 + epb, ne);
  for (int i = e0 + t; i < e1; i += 256) atomicAdd(&cnt[dst[i] >> 8], 1);
  __syncthreads();
  for (int i = t; i < nbuck; i += 256) {
    const int c = cnt[i];
    if (c) atomicAdd(&bhist[i], c);
  }
}

__global__ __launch_bounds__(512) void bscan_k(const int* __restrict__ bhist,
                                               int* __restrict__ base,
                                               int* __restrict__ cursor,
                                               int nbuck, int ne) {
  __shared__ int lds[512];
  const int t = threadIdx.x;
  const int v = t < nbuck ? bhist[t] : 0;
  lds[t] = v;
  __syncthreads();
  for (int o = 1; o < 512; o <<= 1) {
    const int u = t >= o ? lds[t - o] : 0;
    __syncthreads();
    lds[t] += u;
    __syncthreads();
  }
  if (t < nbuck) {
    const int ex = lds[t] - v;
    base[t] = ex;
    cursor[t] = ex;
  }
  if (t == 0) base[nbuck] = ne;
}

__global__ __launch_bounds__(256) void bscat_k(const int* __restrict__ src,
                                               const int* __restrict__ dst,
                                               int* __restrict__ cursor,
                                               u32* __restrict__ tmp, int ne,
                                               int nbuck, int epb) {
  __shared__ int cnt[NBUCK_C];
  __shared__ int gbase[NBUCK_C];
  const int t = threadIdx.x;
  for (int i = t; i < nbuck; i += 256) cnt[i] = 0;
  __syncthreads();
  const int e0 = blockIdx.x * epb;
  const int e1 = min(e0 + epb, ne);
  for (int i = e0 + t; i < e1; i += 256) atomicAdd(&cnt[dst[i] >> 8], 1);
  __syncthreads();
  for (int i = t; i < nbuck; i += 256) {
    const int c = cnt[i];
    gbase[i] = c ? atomicAdd(&cursor[i], c) : 0;
    cnt[i] = 0;
  }
  __syncthreads();
  for (int i = e0 + t; i < e1; i += 256) {
    const int d = dst[i];
    const int b = d >> 8;
    const int p = atomicAdd(&cnt[b], 1);
    tmp[gbase[b] + p] = ((u32)src[i] << 8) | (u32)(d & 255);
  }
}

__global__ __launch_bounds__(256) void bsort_k(const u32* __restrict__ tmp,
                                               const int* __restrict__ base,
                                               int* __restrict__ rp,
                                               int* __restrict__ csr, int n) {
  const int b = blockIdx.x;
  const int t = threadIdx.x;
  __shared__ int cnt[256];
  __shared__ int loc[256];
  const int segbase = base[b];
  const int len = base[b + 1] - segbase;
  cnt[t] = 0;
  __syncthreads();
  for (int i = t; i < len; i += 256) atomicAdd(&cnt[tmp[segbase + i] & 255], 1);
  __syncthreads();
  const int own = cnt[t];
  __syncthreads();
  for (int o = 1; o < 256; o <<= 1) {
    const int u = t >= o ? cnt[t - o] : 0;
    __syncthreads();
    cnt[t] += u;
    __syncthreads();
  }
  const int pre = cnt[t] - own;
  loc[t] = pre;
  const int gnode = b * 256 + t;
  if (gnode <= n) rp[gnode] = segbase + pre;  // includes rp[N]=NE sentinel
  __syncthreads();
  for (int i = t; i < len; i += 256) {
    const u32 v = tmp[segbase + i];
    const int p = atomicAdd(&loc[v & 255], 1);
    csr[segbase + p] = (int)(v >> 8);
  }
}

// per-dst neighbor max: 8 lanes/node, uint4 (8 bf16)/lane, 32 nodes/block.
__global__ __launch_bounds__(256) void gather_k(
    const u16* __restrict__ m, const int* __restrict__ csr,
    const int* __restrict__ rp, u16* __restrict__ agg, int n) {
  const int t = threadIdx.x;
  const int v = blockIdx.x * 32 + (t >> 3);
  if (v >= n) return;
  const int l = t & 7;
  const int base = rp[v];
  const int dg = rp[v + 1] - base;
  uint4 mx = make_uint4(0u, 0u, 0u, 0u);
  int i = 0;
  for (; i + 4 <= dg; i += 4) {
    const int u0 = csr[base + i + 0];
    const int u1 = csr[base + i + 1];
    const int u2 = csr[base + i + 2];
    const int u3 = csr[base + i + 3];
    const uint4 v0 = *(const uint4*)&m[(size_t)u0 * 64 + l * 8];
    const uint4 v1 = *(const uint4*)&m[(size_t)u1 * 64 + l * 8];
    const uint4 v2 = *(const uint4*)&m[(size_t)u2 * 64 + l * 8];
    const uint4 v3 = *(const uint4*)&m[(size_t)u3 * 64 + l * 8];
    mx = mx4(mx, mx4(mx4(v0, v1), mx4(v2, v3)));
  }
  for (; i < dg; ++i) {
    const int u = csr[base + i];
    const uint4 val = *(const uint4*)&m[(size_t)u * 64 + l * 8];
    mx = mx4(mx, val);
  }
  *(uint4*)&agg[(size_t)v * 64 + l * 8] = mx;
}

extern "C" void kernel_launch(void* const* d_in, const int* in_sizes, int n_in,
                              void* d_out, int out_size, void* d_ws,
                              size_t ws_size, hipStream_t stream) {
  const int N = 100000;
  const int NE = in_sizes[2];
  const float* x0 = (const float*)d_in[0];
  const float* x1 = (const float*)d_in[1];
  const int* src = (const int*)d_in[2];
  const int* dst = (const int*)d_in[3];
  auto F = [&](int i) { return (const float*)d_in[i]; };

  char* wsb = (char*)d_ws;
  size_t off = 0;
  auto alloc = [&](size_t bytes) {
    void* p = wsb + off;
    off += (bytes + 255) & ~(size_t)255;
    return p;
  };
  float* Wcf0 = (float*)alloc(64 * 500 * 4);
  float* Wcf1 = (float*)alloc(64 * 500 * 4);
  float* cc0 = (float*)alloc(64 * 4);
  float* cc1 = (float*)alloc(64 * 4);
  u16* Weff0b = (u16*)alloc(64 * 512 * 2);
  u16* Weff1b = (u16*)alloc(64 * 256 * 2);
  float* beff0 = (float*)alloc(64 * 4);
  float* beff1 = (float*)alloc(64 * 4);
  u16* swb[9];
  const int swsrc[9] = {32, 34, 35, 37, 39, 40, 42, 44, 45};
  const int swn[9] = {4096, 4096, 4096, 4096, 4096, 4096, 4096, 512, 512};
  for (int i = 0; i < 9; ++i) swb[i] = (u16*)alloc(swn[i] * 2);
  u16* featb = (u16*)alloc((size_t)N * 64 * 2);
  u16* mb = (u16*)alloc((size_t)N * 64 * 2);
  u16* aggb = (u16*)alloc((size_t)N * 64 * 2);
  u16* h1b = (u16*)alloc((size_t)N * 64 * 2);
  u16* h2b = (u16*)alloc((size_t)N * 64 * 2);
  const int NBUCK = (N + 255) / 256;  // 391 < NBUCK_C
  int* rp = (int*)alloc((size_t)(N + 1) * 4);
  int* csr = (int*)alloc((size_t)NE * 4);
  u32* tmp = (u32*)alloc((size_t)NE * 4);
  int* bhist = (int*)alloc((size_t)NBUCK * 4);
  int* base = (int*)alloc((size_t)(NBUCK + 1) * 4);
  int* cursor = (int*)alloc((size_t)NBUCK * 4);
  (void)n_in; (void)ws_size;

  // weight prep
  WConv wc;
  for (int i = 0; i < 9; ++i) {
    wc.src[i] = F(swsrc[i]); wc.dst[i] = swb[i]; wc.n[i] = swn[i];
  }
  wconv_k<<<dim3(8, 9), 256, 0, stream>>>(wc);
  combine_wcf<<<dim3(2, 64), 256, 0, stream>>>(F(10), F(11), F(12), F(13),
                                               F(14), F(15), F(16), F(17),
                                               Wcf0, cc0);
  combine_wcf<<<dim3(2, 64), 256, 0, stream>>>(F(24), F(25), F(26), F(27),
                                               F(28), F(29), F(30), F(31),
                                               Wcf1, cc1);
  weff2_k<<<dim3(8, 64), 256, 0, stream>>>(Wcf0, cc0, F(6), F(7), F(5), F(8),
                                           F(9), F(4), 512, Weff0b, beff0);
  weff2_k<<<dim3(4, 64), 256, 0, stream>>>(Wcf1, cc1, F(20), F(21), F(19),
                                           F(22), F(23), F(18), 256, Weff1b,
                                           beff1);

  // bucket-sorted CSR build (block-privatized histogram + scatter)
  const int NSB = 512;
  const int EPB = (NE + NSB - 1) / NSB;
  hipMemsetAsync(bhist, 0, (size_t)NBUCK * 4, stream);
  bhist_k<<<NSB, 256, 0, stream>>>(dst, bhist, NE, NBUCK, EPB);
  bscan_k<<<1, 512, 0, stream>>>(bhist, base, cursor, NBUCK, NE);
  bscat_k<<<NSB, 256, 0, stream>>>(src, dst, cursor, tmp, NE, NBUCK, EPB);
  bsort_k<<<NBUCK, 256, 0, stream>>>(tmp, base, rp, csr, N);

  // encoder + fused layer-0 pool (BM=64, all-reg-staged)
  enc_fused64<<<(N + 63) / 64, 256, 0, stream>>>(x0, x1, Weff0b, Weff1b,
                                                 beff0, beff1, swb[0], F(33),
                                                 featb, mb, N);

  const int gx = (N + 127) / 128;
  const int gg = (N + 31) / 32;
  // layer 0 out + layer 1 pool
  gather_k<<<gg, 256, 0, stream>>>(mb, csr, rp, aggb, N);
  sage_fused<<<gx, 256, 0, stream>>>(featb, aggb, swb[1], swb[2], F(36),
                                     swb[3], F(38), h1b, mb, N);
  // layer 1 out + layer 2 pool
  gather_k<<<gg, 256, 0, stream>>>(mb, csr, rp, aggb, N);
  sage_fused<<<gx, 256, 0, stream>>>(h1b, aggb, swb[4], swb[5], F(41),
                                     swb[6], F(43), h2b, mb, N);
  // layer 2 out (final, fp32, CN=8)
  gather_k<<<gg, 256, 0, stream>>>(mb, csr, rp, aggb, N);
  gemm_mfma<64, 0, true, false, false, float><<<gx, 256, 0, stream>>>(
      h2b, 64, swb[7], 64, aggb, swb[8], d_out, 8, N, 8, 64, 8, 1, F(46),
      nullptr, nullptr, nullptr, nullptr, nullptr);
  (void)out_size;
}